// Round 5
// baseline (76.922 us; speedup 1.0000x reference)
//
#include <hip/hip_runtime.h>

#define BATCH 4
#define NPTS 8192
#define PTOT (BATCH * NPTS)   // 32768 points per cloud
#define NJH 4                 // column-range splits
#define TILES (NPTS / 32 / NJH)   // 64 col-tiles per jh range

typedef __attribute__((ext_vector_type(8))) short short8;     // 8 bf16 = 4 VGPRs
typedef __attribute__((ext_vector_type(16))) float f32x16;    // MFMA 32x32 accumulator

__device__ __forceinline__ ushort f2bf(float f) {             // RNE float->bf16 bits
    unsigned u = __float_as_uint(f);
    unsigned r = (u + 0x7fffu + ((u >> 16) & 1u)) >> 16;
    return (ushort)r;
}
__device__ __forceinline__ float bf2f(ushort b) {
    return __uint_as_float(((unsigned)b) << 16);
}

// ---------------------------------------------------------------------------
// Panels: [cloud][PTOT][16] bf16.  For point p with coords c, n2 = |c|^2:
//   A row: [ch0,ch1,ch2, cl0,cl1,cl2, ch0,ch1,ch2, cl0,cl1,cl2, n2h, n2l, 1, 1]
//   B row: [-2ch0..2, -2ch0..2, -2cl0..2, -2cl0..2, 1, 1, n2h, n2l]
// A_n . B_m = -2*(xh+xl).(yh+yl) + x2h+x2l + y2h+y2l  ~= ||x-y||^2
// ---------------------------------------------------------------------------
__global__ __launch_bounds__(256) void pack_k(const float* __restrict__ pred,
                                              const float* __restrict__ tgt,
                                              ushort* __restrict__ Apan,
                                              ushort* __restrict__ Bpan) {
    int i = blockIdx.x * 256 + threadIdx.x;      // [0, 2*PTOT), cloud-major
    int cloud = (i >= PTOT) ? 1 : 0;
    int j = cloud ? i - PTOT : i;
    const float* s = cloud ? tgt : pred;
    float c0 = s[3 * j + 0], c1 = s[3 * j + 1], c2 = s[3 * j + 2];
    float c[3] = {c0, c1, c2};
    ushort hh[3], ll[3], mh[3], ml[3];
#pragma unroll
    for (int d = 0; d < 3; ++d) {
        ushort h = f2bf(c[d]); float hf = bf2f(h);
        ushort l = f2bf(c[d] - hf); float lf = bf2f(l);   // exact residual split
        hh[d] = h; ll[d] = l;
        mh[d] = f2bf(-2.0f * hf);                         // exact (pow2 scale)
        ml[d] = f2bf(-2.0f * lf);
    }
    float n2 = fmaf(c0, c0, fmaf(c1, c1, c2 * c2));
    ushort n2h = f2bf(n2);
    ushort n2l = f2bf(n2 - bf2f(n2h));
    const ushort ONE = 0x3F80;

    __attribute__((aligned(16))) ushort a[16] = {
        hh[0], hh[1], hh[2], ll[0], ll[1], ll[2],
        hh[0], hh[1], hh[2], ll[0], ll[1], ll[2],
        n2h, n2l, ONE, ONE};
    __attribute__((aligned(16))) ushort b[16] = {
        mh[0], mh[1], mh[2], mh[0], mh[1], mh[2],
        ml[0], ml[1], ml[2], ml[0], ml[1], ml[2],
        ONE, ONE, n2h, n2l};

    ushort* ad = Apan + (size_t)i * 16;
    ushort* bd = Bpan + (size_t)i * 16;
    *(uint4*)ad       = *(const uint4*)a;
    *(uint4*)(ad + 8) = *(const uint4*)(a + 8);
    *(uint4*)bd       = *(const uint4*)b;
    *(uint4*)(bd + 8) = *(const uint4*)(b + 8);
}

// ---------------------------------------------------------------------------
// Grid: 4096 one-wave blocks = jh(4) x dir(2) x batch(4) x strip(128).
// Each wave: 2 row-tiles (64 rows), 64 col-tiles, mfma_f32_32x32x16_bf16.
// Depth-4 B prefetch; 8 MFMA + 64 min3 per 4-tile group; setprio around
// compute. part layout: [jh][dir][batch][NPTS].
// ---------------------------------------------------------------------------
__global__ __launch_bounds__(64) void chamfer_mfma_k(const ushort* __restrict__ Apan,
                                                     const ushort* __restrict__ Bpan,
                                                     float* __restrict__ part) {
    int bid   = blockIdx.x;
    int strip = bid & 127;
    int b     = (bid >> 7) & 3;
    int dir   = (bid >> 9) & 1;
    int jh    = bid >> 10;         // 0..3
    int lane  = threadIdx.x;       // 0..63

    const ushort* Ap = Apan + ((size_t)dir * PTOT + (size_t)b * NPTS) * 16;
    const ushort* Bp = Bpan + ((size_t)(1 - dir) * PTOT + (size_t)b * NPTS) * 16;

    int rowbase = strip * 64;
    // A frags: row = lane&31 (+32 for 2nd tile), k = 8*(lane>>5)+0..7
    const short8 af0 = *reinterpret_cast<const short8*>(
        Ap + (size_t)(rowbase + (lane & 31)) * 16 + 8 * (lane >> 5));
    const short8 af1 = *reinterpret_cast<const short8*>(
        Ap + (size_t)(rowbase + 32 + (lane & 31)) * 16 + 8 * (lane >> 5));

    // B frag base: col = lane&31, k = 8*(lane>>5); tile stride = 512 ushorts
    const ushort* bptr = Bp + (size_t)(lane & 31) * 16 + 8 * (lane >> 5)
                            + (size_t)jh * TILES * 512;

    f32x16 zero = {};
    float run0[16], run1[16];
#pragma unroll
    for (int r = 0; r < 16; ++r) { run0[r] = 1e30f; run1[r] = 1e30f; }

#define LDB(J) (*reinterpret_cast<const short8*>(bptr + (size_t)(J) * 512))
#define STEP(X, Y)                                                              \
    {                                                                           \
        f32x16 a00 = __builtin_amdgcn_mfma_f32_32x32x16_bf16(af0, X, zero, 0, 0, 0); \
        f32x16 a01 = __builtin_amdgcn_mfma_f32_32x32x16_bf16(af0, Y, zero, 0, 0, 0); \
        f32x16 a10 = __builtin_amdgcn_mfma_f32_32x32x16_bf16(af1, X, zero, 0, 0, 0); \
        f32x16 a11 = __builtin_amdgcn_mfma_f32_32x32x16_bf16(af1, Y, zero, 0, 0, 0); \
        _Pragma("unroll")                                                       \
        for (int r = 0; r < 16; ++r) {                                          \
            run0[r] = fminf(run0[r], fminf(a00[r], a01[r]));                    \
            run1[r] = fminf(run1[r], fminf(a10[r], a11[r]));                    \
        }                                                                       \
    }

    // depth-4 software pipeline
    short8 t0 = LDB(0), t1 = LDB(1), t2 = LDB(2), t3 = LDB(3);
    for (int j = 0; j < TILES - 4; j += 4) {
        short8 n0 = LDB(j + 4), n1 = LDB(j + 5), n2 = LDB(j + 6), n3 = LDB(j + 7);
        __builtin_amdgcn_s_setprio(1);
        STEP(t0, t1);
        STEP(t2, t3);
        __builtin_amdgcn_s_setprio(0);
        t0 = n0; t1 = n1; t2 = n2; t3 = n3;
    }
    __builtin_amdgcn_s_setprio(1);
    STEP(t0, t1);
    STEP(t2, t3);
    __builtin_amdgcn_s_setprio(0);
#undef STEP
#undef LDB

    // C/D layout (verified): col = lane&31, row = (r&3)+8*(r>>2)+4*(lane>>5)
    size_t obase = (((size_t)jh * 2 + dir) * BATCH + b) * NPTS + rowbase;
#pragma unroll
    for (int r = 0; r < 16; ++r) {
        float v0 = run0[r];
        float v1 = run1[r];
        v0 = fminf(v0, __shfl_xor(v0, 1, 32));
        v1 = fminf(v1, __shfl_xor(v1, 1, 32));
        v0 = fminf(v0, __shfl_xor(v0, 2, 32));
        v1 = fminf(v1, __shfl_xor(v1, 2, 32));
        v0 = fminf(v0, __shfl_xor(v0, 4, 32));
        v1 = fminf(v1, __shfl_xor(v1, 4, 32));
        v0 = fminf(v0, __shfl_xor(v0, 8, 32));
        v1 = fminf(v1, __shfl_xor(v1, 8, 32));
        v0 = fminf(v0, __shfl_xor(v0, 16, 32));
        v1 = fminf(v1, __shfl_xor(v1, 16, 32));
        if ((lane & 31) == 0) {
            int row = (r & 3) + 8 * (r >> 2) + 4 * (lane >> 5);
            part[obase + row]      = v0;
            part[obase + 32 + row] = v1;
        }
    }
}

// Stage 1: min over NJH splits, clamp, per-block sum (256 blocks).
__global__ __launch_bounds__(256) void reduce1_k(const float* __restrict__ part,
                                                 float* __restrict__ bsum) {
    int q = blockIdx.x * 256 + threadIdx.x;   // [0, 65536)
    float v = part[q];
#pragma unroll
    for (int jh = 1; jh < NJH; ++jh)
        v = fminf(v, part[(size_t)jh * 65536 + q]);
    v = fmaxf(v, 0.0f);
    for (int off = 32; off; off >>= 1) v += __shfl_down(v, off, 64);
    __shared__ float lds[4];
    int lane = threadIdx.x & 63, w = threadIdx.x >> 6;
    if (lane == 0) lds[w] = v;
    __syncthreads();
    if (threadIdx.x == 0)
        bsum[blockIdx.x] = (lds[0] + lds[1]) + (lds[2] + lds[3]);
}

// Stage 2: sum 256 block sums, scale.
__global__ __launch_bounds__(256) void reduce2_k(const float* __restrict__ bsum,
                                                 float* __restrict__ out) {
    float v = bsum[threadIdx.x];
    for (int off = 32; off; off >>= 1) v += __shfl_down(v, off, 64);
    __shared__ float lds[4];
    int lane = threadIdx.x & 63, w = threadIdx.x >> 6;
    if (lane == 0) lds[w] = v;
    __syncthreads();
    if (threadIdx.x == 0)
        out[0] = ((lds[0] + lds[1]) + (lds[2] + lds[3])) * (1.0f / 32768.0f);
}

extern "C" void kernel_launch(void* const* d_in, const int* in_sizes, int n_in,
                              void* d_out, int out_size, void* d_ws, size_t ws_size,
                              hipStream_t stream) {
    const float* pred = (const float*)d_in[0];
    const float* tgt  = (const float*)d_in[1];

    ushort* Apan = (ushort*)d_ws;                          // 2 MB
    ushort* Bpan = Apan + (size_t)2 * PTOT * 16;           // 2 MB
    float*  part = (float*)(Bpan + (size_t)2 * PTOT * 16); // NJH*2*PTOT floats = 1 MB
    float*  bsum = part + (size_t)NJH * 2 * PTOT;          // 256 floats

    pack_k<<<(2 * PTOT) / 256, 256, 0, stream>>>(pred, tgt, Apan, Bpan);
    chamfer_mfma_k<<<NJH * 2 * BATCH * 128, 64, 0, stream>>>(Apan, Bpan, part);
    reduce1_k<<<256, 256, 0, stream>>>(part, bsum);
    reduce2_k<<<1, 256, 0, stream>>>(bsum, (float*)d_out);
}

// Round 7
// 52.890 us; speedup vs baseline: 1.4544x; 1.4544x over previous
//
#include <hip/hip_runtime.h>

#define BATCH 4
#define NPTS 8192
#define PTOT (BATCH * NPTS)   // 32768 points per cloud
#define NJH 8                 // column-range splits
#define TILES (NPTS / 32 / NJH)   // 32 col-tiles per jh range (32 KB LDS)

typedef __attribute__((ext_vector_type(8))) short short8;     // 8 bf16 = 4 VGPRs
typedef __attribute__((ext_vector_type(16))) float f32x16;    // MFMA 32x32 accumulator

__device__ __forceinline__ ushort f2bf(float f) {             // RNE float->bf16 bits
    unsigned u = __float_as_uint(f);
    unsigned r = (u + 0x7fffu + ((u >> 16) & 1u)) >> 16;
    return (ushort)r;
}
__device__ __forceinline__ float bf2f(ushort b) {
    return __uint_as_float(((unsigned)b) << 16);
}

// ---------------------------------------------------------------------------
// k-order (A row must match B's subtiled khalf split!):
//   k 0..5 : A = ch0,ch1,ch2, cl0,cl1,cl2      B = mh0,mh1,mh2, mh0,mh1,mh2
//   k 6..7 : A = n2h, n2l                       B = ONE, ONE
//   k 8..13: A = ch0,ch1,ch2, cl0,cl1,cl2      B = ml0,ml1,ml2, ml0,ml1,ml2
//   k14..15: A = ONE, ONE                       B = n2h, n2l
// A_n . B_m = -2*(xh+xl).(yh+yl) + x2h+x2l + y2h+y2l ~= ||x-y||^2 (exact
// products; only the hi/lo split residual ~2^-17 remains)
// B panel layout: [cloud][batch][tile][khalf][col][8] (subtiled for LDS).
// ---------------------------------------------------------------------------
__global__ __launch_bounds__(256) void pack_k(const float* __restrict__ pred,
                                              const float* __restrict__ tgt,
                                              ushort* __restrict__ Apan,
                                              ushort* __restrict__ Bpan) {
    int i = blockIdx.x * 256 + threadIdx.x;      // [0, 2*PTOT), cloud-major
    int cloud = (i >= PTOT) ? 1 : 0;
    int jg = cloud ? i - PTOT : i;               // [0, PTOT)
    const float* s = cloud ? tgt : pred;
    float c0 = s[3 * jg + 0], c1 = s[3 * jg + 1], c2 = s[3 * jg + 2];
    float c[3] = {c0, c1, c2};
    ushort hh[3], ll[3], mh[3], ml[3];
#pragma unroll
    for (int d = 0; d < 3; ++d) {
        ushort h = f2bf(c[d]); float hf = bf2f(h);
        ushort l = f2bf(c[d] - hf); float lf = bf2f(l);   // exact residual split
        hh[d] = h; ll[d] = l;
        mh[d] = f2bf(-2.0f * hf);                         // exact (pow2 scale)
        ml[d] = f2bf(-2.0f * lf);
    }
    float n2 = fmaf(c0, c0, fmaf(c1, c1, c2 * c2));
    ushort n2h = f2bf(n2);
    ushort n2l = f2bf(n2 - bf2f(n2h));
    const ushort ONE = 0x3F80;

    // A row in the NEW k-order (matches B's khalf split)
    __attribute__((aligned(16))) ushort a[16] = {
        hh[0], hh[1], hh[2], ll[0], ll[1], ll[2], n2h, n2l,
        hh[0], hh[1], hh[2], ll[0], ll[1], ll[2], ONE, ONE};
    __attribute__((aligned(16))) ushort blo[8] = {
        mh[0], mh[1], mh[2], mh[0], mh[1], mh[2], ONE, ONE};   // k = 0..7
    __attribute__((aligned(16))) ushort bhi[8] = {
        ml[0], ml[1], ml[2], ml[0], ml[1], ml[2], n2h, n2l};   // k = 8..15

    ushort* ad = Apan + (size_t)i * 16;
    *(uint4*)ad       = *(const uint4*)a;
    *(uint4*)(ad + 8) = *(const uint4*)(a + 8);

    // B subtiled: batch = jg>>13, loc = jg&8191, tile = loc>>5, col = loc&31
    int loc = jg & (NPTS - 1);
    int t   = loc >> 5;
    int col = loc & 31;
    size_t bb = ((size_t)cloud * PTOT + (size_t)(jg >> 13) * NPTS) * 16
              + (size_t)t * 512 + (size_t)col * 8;
    *(uint4*)(Bpan + bb)       = *(const uint4*)blo;   // khalf 0
    *(uint4*)(Bpan + bb + 256) = *(const uint4*)bhi;   // khalf 1
}

// ---------------------------------------------------------------------------
// Grid: 2048 blocks = jh(8) x dir(2) x batch(4) x strip(32); 256 thr (4 waves).
// Block stages its 32-tile B panel (32 KB) into LDS once; each wave owns
// 2 row-tiles (64 rows) and iterates 32 col-tiles: 2 ds_read_b128 + 4 MFMA +
// 32 min3 per 2-tile step. part layout: [jh][dir][batch][NPTS].
// ---------------------------------------------------------------------------
__global__ __launch_bounds__(256, 4) void chamfer_mfma_k(const ushort* __restrict__ Apan,
                                                         const ushort* __restrict__ Bpan,
                                                         float* __restrict__ part) {
    __shared__ ushort Bsm[TILES * 512];   // 32 KB

    int bid   = blockIdx.x;
    int strip = bid & 31;
    int b     = (bid >> 5) & 3;
    int dir   = (bid >> 7) & 1;
    int jh    = bid >> 8;          // 0..7
    int tid   = threadIdx.x;
    int lane  = tid & 63;
    int wave  = tid >> 6;

    const ushort* Ap = Apan + ((size_t)dir * PTOT + (size_t)b * NPTS) * 16;
    const ushort* Bp = Bpan + ((size_t)(1 - dir) * PTOT + (size_t)b * NPTS) * 16
                            + (size_t)jh * TILES * 512;

    // stage B panel: 32 KB = 2048 float4, 256 threads x 8 iters (coalesced)
    {
        const float4* src = (const float4*)Bp;
        float4* dst = (float4*)Bsm;
#pragma unroll
        for (int it = 0; it < 8; ++it)
            dst[it * 256 + tid] = src[it * 256 + tid];
    }

    int rowbase = strip * 256 + wave * 64;
    // A frags: row = lane&31 (+32 for 2nd tile), k = 8*(lane>>5)+0..7
    const short8 af0 = *reinterpret_cast<const short8*>(
        Ap + (size_t)(rowbase + (lane & 31)) * 16 + 8 * (lane >> 5));
    const short8 af1 = *reinterpret_cast<const short8*>(
        Ap + (size_t)(rowbase + 32 + (lane & 31)) * 16 + 8 * (lane >> 5));

    __syncthreads();

    // B frag in LDS: tile j -> j*512 + (lane>>5)*256 + (lane&31)*8 (ushorts)
    const ushort* bbase = Bsm + (size_t)(lane >> 5) * 256 + (size_t)(lane & 31) * 8;

    f32x16 zero = {};
    float run0[16], run1[16];
#pragma unroll
    for (int r = 0; r < 16; ++r) { run0[r] = 1e30f; run1[r] = 1e30f; }

#pragma unroll 2
    for (int j = 0; j < TILES; j += 2) {
        short8 c0 = *reinterpret_cast<const short8*>(bbase + (size_t)j * 512);
        short8 c1 = *reinterpret_cast<const short8*>(bbase + (size_t)j * 512 + 512);
        f32x16 a0 = __builtin_amdgcn_mfma_f32_32x32x16_bf16(af0, c0, zero, 0, 0, 0);
        f32x16 a1 = __builtin_amdgcn_mfma_f32_32x32x16_bf16(af0, c1, zero, 0, 0, 0);
#pragma unroll
        for (int r = 0; r < 16; ++r)
            run0[r] = fminf(run0[r], fminf(a0[r], a1[r]));   // v_min3_f32
        f32x16 a2 = __builtin_amdgcn_mfma_f32_32x32x16_bf16(af1, c0, zero, 0, 0, 0);
        f32x16 a3 = __builtin_amdgcn_mfma_f32_32x32x16_bf16(af1, c1, zero, 0, 0, 0);
#pragma unroll
        for (int r = 0; r < 16; ++r)
            run1[r] = fminf(run1[r], fminf(a2[r], a3[r]));
    }

    // C/D layout (verified): col = lane&31, row = (r&3)+8*(r>>2)+4*(lane>>5)
    size_t obase = (((size_t)jh * 2 + dir) * BATCH + b) * NPTS + rowbase;
#pragma unroll
    for (int r = 0; r < 16; ++r) {
        float v0 = run0[r];
        float v1 = run1[r];
        v0 = fminf(v0, __shfl_xor(v0, 1, 32));
        v1 = fminf(v1, __shfl_xor(v1, 1, 32));
        v0 = fminf(v0, __shfl_xor(v0, 2, 32));
        v1 = fminf(v1, __shfl_xor(v1, 2, 32));
        v0 = fminf(v0, __shfl_xor(v0, 4, 32));
        v1 = fminf(v1, __shfl_xor(v1, 4, 32));
        v0 = fminf(v0, __shfl_xor(v0, 8, 32));
        v1 = fminf(v1, __shfl_xor(v1, 8, 32));
        v0 = fminf(v0, __shfl_xor(v0, 16, 32));
        v1 = fminf(v1, __shfl_xor(v1, 16, 32));
        if ((lane & 31) == 0) {
            int row = (r & 3) + 8 * (r >> 2) + 4 * (lane >> 5);
            part[obase + row]      = v0;
            part[obase + 32 + row] = v1;
        }
    }
}

// Stage 1: min over NJH splits, clamp, per-block sum (256 blocks).
__global__ __launch_bounds__(256) void reduce1_k(const float* __restrict__ part,
                                                 float* __restrict__ bsum) {
    int q = blockIdx.x * 256 + threadIdx.x;   // [0, 65536)
    float v = part[q];
#pragma unroll
    for (int jh = 1; jh < NJH; ++jh)
        v = fminf(v, part[(size_t)jh * 65536 + q]);
    v = fmaxf(v, 0.0f);
    for (int off = 32; off; off >>= 1) v += __shfl_down(v, off, 64);
    __shared__ float lds[4];
    int lane = threadIdx.x & 63, w = threadIdx.x >> 6;
    if (lane == 0) lds[w] = v;
    __syncthreads();
    if (threadIdx.x == 0)
        bsum[blockIdx.x] = (lds[0] + lds[1]) + (lds[2] + lds[3]);
}

// Stage 2: sum 256 block sums, scale.
__global__ __launch_bounds__(256) void reduce2_k(const float* __restrict__ bsum,
                                                 float* __restrict__ out) {
    float v = bsum[threadIdx.x];
    for (int off = 32; off; off >>= 1) v += __shfl_down(v, off, 64);
    __shared__ float lds[4];
    int lane = threadIdx.x & 63, w = threadIdx.x >> 6;
    if (lane == 0) lds[w] = v;
    __syncthreads();
    if (threadIdx.x == 0)
        out[0] = ((lds[0] + lds[1]) + (lds[2] + lds[3])) * (1.0f / 32768.0f);
}

extern "C" void kernel_launch(void* const* d_in, const int* in_sizes, int n_in,
                              void* d_out, int out_size, void* d_ws, size_t ws_size,
                              hipStream_t stream) {
    const float* pred = (const float*)d_in[0];
    const float* tgt  = (const float*)d_in[1];

    ushort* Apan = (ushort*)d_ws;                          // 2 MB
    ushort* Bpan = Apan + (size_t)2 * PTOT * 16;           // 2 MB
    float*  part = (float*)(Bpan + (size_t)2 * PTOT * 16); // NJH*2*PTOT floats = 2 MB
    float*  bsum = part + (size_t)NJH * 2 * PTOT;          // 256 floats

    pack_k<<<(2 * PTOT) / 256, 256, 0, stream>>>(pred, tgt, Apan, Bpan);
    chamfer_mfma_k<<<NJH * 2 * BATCH * 32, 256, 0, stream>>>(Apan, Bpan, part);
    reduce1_k<<<256, 256, 0, stream>>>(part, bsum);
    reduce2_k<<<1, 256, 0, stream>>>(bsum, (float*)d_out);
}

// Round 8
// 32.354 us; speedup vs baseline: 2.3775x; 1.6347x over previous
//
#include <hip/hip_runtime.h>

#define BATCH 4
#define NPTS 8192
#define PTOT (BATCH * NPTS)   // 32768 points per cloud
#define NJH 16                // ref-range splits
#define TILES (NPTS / 32 / NJH)   // 16 ref-tiles per jh range (16 KB LDS)
#define QREP 2                // query phases per block (reuse staged refs)

typedef __attribute__((ext_vector_type(8))) short short8;     // 8 bf16 = 4 VGPRs
typedef __attribute__((ext_vector_type(16))) float f32x16;    // MFMA 32x32 accumulator

__device__ __forceinline__ ushort f2bf(float f) {             // RNE float->bf16 bits
    unsigned u = __float_as_uint(f);
    unsigned r = (u + 0x7fffu + ((u >> 16) & 1u)) >> 16;
    return (ushort)r;
}
__device__ __forceinline__ float bf2f(ushort b) {
    return __uint_as_float(((unsigned)b) << 16);
}

// 8-min3 tree: fold 16 MFMA outputs + carry into one scalar (all fminf pairs
// fuse to v_min3_f32; depth 3).
__device__ __forceinline__ float tree16(const f32x16 a, float run) {
    float m0 = fminf(fminf(a[0],  a[1]),  a[2]);
    float m1 = fminf(fminf(a[3],  a[4]),  a[5]);
    float m2 = fminf(fminf(a[6],  a[7]),  a[8]);
    float m3 = fminf(fminf(a[9],  a[10]), a[11]);
    float m4 = fminf(fminf(a[12], a[13]), a[14]);
    float n0 = fminf(fminf(m0, m1), m2);
    float n1 = fminf(fminf(m3, m4), a[15]);
    return fminf(run, fminf(n0, n1));
}

// ---------------------------------------------------------------------------
// k-order (A-content row must match B-content's khalf split):
//   k 0..5 : Q = ch0,ch1,ch2, cl0,cl1,cl2      R = mh0,mh1,mh2, mh0,mh1,mh2
//   k 6..7 : Q = n2h, n2l                       R = ONE, ONE
//   k 8..13: Q = ch0,ch1,ch2, cl0,cl1,cl2      R = ml0,ml1,ml2, ml0,ml1,ml2
//   k14..15: Q = ONE, ONE                       R = n2h, n2l
// Q_n . R_m = -2*(xh+xl).(yh+yl) + x2 + y2 ~= ||x-y||^2 (products exact;
// only hi/lo split residual ~2^-17 remains). Dot is symmetric, so the
// R-panel (subtiled) feeds the MFMA A slot and the Q-panel the B slot.
// Qpan: [cloud][PTOT][16] row-major. Rpan: [cloud][batch][tile][khalf][col][8].
// ---------------------------------------------------------------------------
__global__ __launch_bounds__(256) void pack_k(const float* __restrict__ pred,
                                              const float* __restrict__ tgt,
                                              ushort* __restrict__ Qpan,
                                              ushort* __restrict__ Rpan) {
    int i = blockIdx.x * 256 + threadIdx.x;      // [0, 2*PTOT), cloud-major
    int cloud = (i >= PTOT) ? 1 : 0;
    int jg = cloud ? i - PTOT : i;               // [0, PTOT)
    const float* s = cloud ? tgt : pred;
    float c0 = s[3 * jg + 0], c1 = s[3 * jg + 1], c2 = s[3 * jg + 2];
    float c[3] = {c0, c1, c2};
    ushort hh[3], ll[3], mh[3], ml[3];
#pragma unroll
    for (int d = 0; d < 3; ++d) {
        ushort h = f2bf(c[d]); float hf = bf2f(h);
        ushort l = f2bf(c[d] - hf); float lf = bf2f(l);   // exact residual split
        hh[d] = h; ll[d] = l;
        mh[d] = f2bf(-2.0f * hf);                         // exact (pow2 scale)
        ml[d] = f2bf(-2.0f * lf);
    }
    float n2 = fmaf(c0, c0, fmaf(c1, c1, c2 * c2));
    ushort n2h = f2bf(n2);
    ushort n2l = f2bf(n2 - bf2f(n2h));
    const ushort ONE = 0x3F80;

    __attribute__((aligned(16))) ushort a[16] = {
        hh[0], hh[1], hh[2], ll[0], ll[1], ll[2], n2h, n2l,
        hh[0], hh[1], hh[2], ll[0], ll[1], ll[2], ONE, ONE};
    __attribute__((aligned(16))) ushort blo[8] = {
        mh[0], mh[1], mh[2], mh[0], mh[1], mh[2], ONE, ONE};   // k = 0..7
    __attribute__((aligned(16))) ushort bhi[8] = {
        ml[0], ml[1], ml[2], ml[0], ml[1], ml[2], n2h, n2l};   // k = 8..15

    ushort* ad = Qpan + (size_t)i * 16;
    *(uint4*)ad       = *(const uint4*)a;
    *(uint4*)(ad + 8) = *(const uint4*)(a + 8);

    int loc = jg & (NPTS - 1);
    int t   = loc >> 5;
    int col = loc & 31;
    size_t bb = ((size_t)cloud * PTOT + (size_t)(jg >> 13) * NPTS) * 16
              + (size_t)t * 512 + (size_t)col * 8;
    *(uint4*)(Rpan + bb)       = *(const uint4*)blo;   // khalf 0
    *(uint4*)(Rpan + bb + 256) = *(const uint4*)bhi;   // khalf 1
}

// ---------------------------------------------------------------------------
// Grid: 4096 blocks = jh(16) x dir(2) x batch(4) x qblk(32); 256 thr (4 waves).
// Block stages its 16-tile ref panel (16 KB) into LDS once, then runs QREP=2
// query phases. Per wave-phase: 32 queries (lane&31), 16 ref-tiles:
// 1 ds_read_b128 + 1 MFMA + 8 min3 each, min into a SCALAR run (lane-local,
// since C col=lane=query). Epilogue: shfl_xor(32) + 1 min + 32-float store.
// part layout: [jh][dir][batch][NPTS].
// ---------------------------------------------------------------------------
__global__ __launch_bounds__(256, 6) void chamfer_mfma_k(const ushort* __restrict__ Qpan,
                                                         const ushort* __restrict__ Rpan,
                                                         float* __restrict__ part) {
    __shared__ ushort Rsm[TILES * 512];   // 16 KB

    int bid  = blockIdx.x;
    int qblk = bid & 31;
    int b    = (bid >> 5) & 3;
    int dir  = (bid >> 7) & 1;
    int jh   = bid >> 8;           // 0..15
    int tid  = threadIdx.x;
    int lane = tid & 63;
    int wave = tid >> 6;

    const ushort* Qp = Qpan + ((size_t)dir * PTOT + (size_t)b * NPTS) * 16;
    const ushort* Rp = Rpan + ((size_t)(1 - dir) * PTOT + (size_t)b * NPTS) * 16
                            + (size_t)jh * TILES * 512;

    // stage ref panel: 16 KB = 1024 float4, 256 threads x 4 iters (coalesced)
    {
        const float4* src = (const float4*)Rp;
        float4* dst = (float4*)Rsm;
#pragma unroll
        for (int it = 0; it < 4; ++it)
            dst[it * 256 + tid] = src[it * 256 + tid];
    }
    __syncthreads();

    // A-slot frag from LDS: tile t -> t*512 + (lane>>5)*256 + (lane&31)*8
    const ushort* rbase = Rsm + (size_t)(lane >> 5) * 256 + (size_t)(lane & 31) * 8;

    f32x16 zero = {};
    size_t pbase = (((size_t)jh * 2 + dir) * BATCH + b) * NPTS;

#pragma unroll
    for (int qs = 0; qs < QREP; ++qs) {
        int q = qblk * 256 + qs * 128 + wave * 32;
        // B-slot frag: col = lane&31 (query), khalf = lane>>5
        const short8 qf = *reinterpret_cast<const short8*>(
            Qp + (size_t)(q + (lane & 31)) * 16 + 8 * (lane >> 5));

        float run = 1e30f;
#pragma unroll 2
        for (int t = 0; t < TILES; t += 2) {
            short8 r0 = *reinterpret_cast<const short8*>(rbase + (size_t)t * 512);
            short8 r1 = *reinterpret_cast<const short8*>(rbase + (size_t)t * 512 + 512);
            f32x16 acc0 = __builtin_amdgcn_mfma_f32_32x32x16_bf16(r0, qf, zero, 0, 0, 0);
            f32x16 acc1 = __builtin_amdgcn_mfma_f32_32x32x16_bf16(r1, qf, zero, 0, 0, 0);
            run = tree16(acc0, run);
            run = tree16(acc1, run);
        }
        // rows are split across lane halves (row has +4*(lane>>5)): combine
        run = fminf(run, __shfl_xor(run, 32, 64));
        if (lane < 32)
            part[pbase + q + lane] = run;
    }
}

// Stage 1: min over NJH splits, clamp, per-block sum (256 blocks).
__global__ __launch_bounds__(256) void reduce1_k(const float* __restrict__ part,
                                                 float* __restrict__ bsum) {
    int q = blockIdx.x * 256 + threadIdx.x;   // [0, 65536)
    float v = part[q];
#pragma unroll
    for (int jh = 1; jh < NJH; ++jh)
        v = fminf(v, part[(size_t)jh * 65536 + q]);
    v = fmaxf(v, 0.0f);
    for (int off = 32; off; off >>= 1) v += __shfl_down(v, off, 64);
    __shared__ float lds[4];
    int lane = threadIdx.x & 63, w = threadIdx.x >> 6;
    if (lane == 0) lds[w] = v;
    __syncthreads();
    if (threadIdx.x == 0)
        bsum[blockIdx.x] = (lds[0] + lds[1]) + (lds[2] + lds[3]);
}

// Stage 2: sum 256 block sums, scale.
__global__ __launch_bounds__(256) void reduce2_k(const float* __restrict__ bsum,
                                                 float* __restrict__ out) {
    float v = bsum[threadIdx.x];
    for (int off = 32; off; off >>= 1) v += __shfl_down(v, off, 64);
    __shared__ float lds[4];
    int lane = threadIdx.x & 63, w = threadIdx.x >> 6;
    if (lane == 0) lds[w] = v;
    __syncthreads();
    if (threadIdx.x == 0)
        out[0] = ((lds[0] + lds[1]) + (lds[2] + lds[3])) * (1.0f / 32768.0f);
}

extern "C" void kernel_launch(void* const* d_in, const int* in_sizes, int n_in,
                              void* d_out, int out_size, void* d_ws, size_t ws_size,
                              hipStream_t stream) {
    const float* pred = (const float*)d_in[0];
    const float* tgt  = (const float*)d_in[1];

    ushort* Qpan = (ushort*)d_ws;                          // 2 MB
    ushort* Rpan = Qpan + (size_t)2 * PTOT * 16;           // 2 MB
    float*  part = (float*)(Rpan + (size_t)2 * PTOT * 16); // NJH*2*PTOT floats = 4 MB
    float*  bsum = part + (size_t)NJH * 2 * PTOT;          // 256 floats

    pack_k<<<(2 * PTOT) / 256, 256, 0, stream>>>(pred, tgt, Qpan, Rpan);
    chamfer_mfma_k<<<NJH * 2 * BATCH * 32, 256, 0, stream>>>(Qpan, Rpan, part);
    reduce1_k<<<256, 256, 0, stream>>>(part, bsum);
    reduce2_k<<<1, 256, 0, stream>>>(bsum, (float*)d_out);
}